// Round 14
// baseline (452.042 us; speedup 1.0000x reference)
//
#include <hip/hip_runtime.h>
#include <hip/hip_bf16.h>
#include <cstdint>

// Problem constants (fixed by the reference)
#define NB 4            // batch
#define NS 2048         // sequence
#define ND 512          // feature dim
#define NM 2048         // MAX_LEN (clamp M)
#define NV 4097         // table rows = 2M+1
#define NP 3000         // POS_MAX
#define RSW 3080        // rs table row stride
#define EBI_KB 129      // kb tiles per dt (EVW=4128 / 32)
#define HTI_BATCH_BYTES (2 * 256 * 1024)   // 2 phases x 256 tblk x 1KB
#define RQ 3072         // R rows per batch
#define RHALF 6291456   // elements per R half = NB*RQ*ND

typedef __bf16 bf16x8 __attribute__((ext_vector_type(8)));
typedef float f32x4 __attribute__((ext_vector_type(4)));

__device__ __forceinline__ unsigned short f2bf(float f) {
  union { __bf16 b; unsigned short u; } cv;
  cv.b = (__bf16)f;
  return cv.u;
}
__device__ __forceinline__ float bfbits2f(unsigned int u) {
  return __uint_as_float(u << 16);
}

__device__ __forceinline__ int lbound_dev(const int* a, int n, int key) {
  int lo = 0, hi = n;
  while (lo < hi) { int mid = (lo + hi) >> 1; if (a[mid] < key) lo = mid + 1; else hi = mid; }
  return lo;  // count of elements < key
}

// ---------- k_prep: ALL prep in one launch (r12-identical) ----------
__global__ void k_prep(const int* __restrict__ pos, const float* __restrict__ emb,
                       unsigned short* __restrict__ HTI, unsigned short* __restrict__ EBI,
                       int* __restrict__ rs) {
  __shared__ float tile[64][65];
  __shared__ unsigned int h[NP];
  int blk = blockIdx.x, tid = threadIdx.x;
  if (blk < 52) {
    int b = blk & 3, chunk = blk >> 2;
    int t = chunk * 256 + tid;
    if (t <= 3072) rs[b * RSW + t] = lbound_dev(pos + b * NS, NS, t);
    return;
  }
  if (blk < 564) {
    int idx = (blk - 52) * 256 + tid;            // 131072 = 4b x 2p x 256tb x 64l
    int bb = idx >> 15;                          // uniform per block
    for (int i = tid; i < NP; i += 256) h[i] = 0u;
    __syncthreads();
    const int* pb = pos + bb * NS;
    for (int i = tid; i < NS; i += 256) atomicAdd(&h[pb[i]], 1u);
    __syncthreads();
    int l = idx & 63;
    int tb = (idx >> 6) & 255;
    int p = (idx >> 14) & 1;
    int base = 5104 + (l & 15) - tb * 32 - p * 16 - ((l >> 4) * 8);
    union { unsigned short us[8]; uint4 v4; } pk;
#pragma unroll
    for (int e = 0; e < 8; ++e) {
      int ii = base - e;
      float f = (ii >= 0 && ii < NP) ? (float)h[ii] : 0.0f;
      pk.us[e] = f2bf(f);
    }
    *(uint4*)(HTI + ((size_t)(bb * 2 + p) * 256 + tb) * 512 + l * 8) = pk.v4;
    return;
  }
  {
    int blk2 = blk - 564;                        // 520 = 65 v-tiles x 8 d-tiles
    int v0 = (blk2 % 65) * 64, d0 = (blk2 / 65) * 64;
    int c = tid & 63, r0 = tid >> 6;
#pragma unroll
    for (int k = 0; k < 16; ++k) {
      int r = k * 4 + r0;
      int v = v0 + r;
      float val = 0.f;
      if (v < NV && v != 0 && v != (NV - 1)) val = emb[(size_t)v * ND + d0 + c];
      tile[r][c] = val;
    }
    __syncthreads();
#pragma unroll
    for (int rep = 0; rep < 2; ++rep) {
      int tile_id = rep * 4 + (tid >> 6);
      int l = tid & 63;
      int kb_loc = tile_id >> 2, dt_loc = tile_id & 3;
      int kb = (v0 >> 5) + kb_loc, dt = (d0 >> 4) + dt_loc;
      if (kb < EBI_KB) {
        union { unsigned short us[8]; uint4 v4; } pk;
#pragma unroll
        for (int e = 0; e < 8; ++e)
          pk.us[e] = f2bf(tile[kb_loc * 32 + ((l >> 4) * 8) + e][dt_loc * 16 + (l & 15)]);
        *(uint4*)(EBI + ((size_t)dt * EBI_KB + kb) * 512 + l * 8) = pk.v4;
      }
    }
  }
}

// ---------- k4s: split-K direct-to-register Toeplitz GEMM -> partial R (bf16) ----------
// r8 per-step structure EXACTLY (32q x 64d wave tile, acc[2][4], 8 MFMA + 6 coalesced
// 1KB loads/step, depth-2 3-set rotation, no LDS, no barriers). Split-K x2: each block
// handles half the K-window -> 1536 blocks = 6144 waves = 24 waves/CU (2x TLP; r13
// diagnosis: latency-bound, occupancy grid-limited). Partial sums -> R[h][b][q][d] bf16;
// boundary terms + x-add moved to k5. XCD swizzle: XCD j = db-slice j (EBI slice 0.5MB
// + HTI 2MB < 4MiB L2).
#define LOADSET(sa0, sa1, sb0, sb1, sb2, sb3, tt)                                   \
  if ((tt) < nt) {                                                                  \
    int tof = (tt) * 1024 + vo;                                                     \
    sa0 = *(const bf16x8*)(hb + (size_t)(cA0 + tof));                               \
    sa1 = *(const bf16x8*)(hb + (size_t)(cA1 + tof));                               \
    sb0 = *(const bf16x8*)(eb + (size_t)(cB0 + tof));                               \
    sb1 = *(const bf16x8*)(eb + (size_t)(cB1 + tof));                               \
    sb2 = *(const bf16x8*)(eb + (size_t)(cB2 + tof));                               \
    sb3 = *(const bf16x8*)(eb + (size_t)(cB3 + tof));                               \
  }

#define MMSET(sa0, sa1, sb0, sb1, sb2, sb3)                                         \
  acc[0][0] = __builtin_amdgcn_mfma_f32_16x16x32_bf16(sa0, sb0, acc[0][0], 0, 0, 0);\
  acc[0][1] = __builtin_amdgcn_mfma_f32_16x16x32_bf16(sa0, sb1, acc[0][1], 0, 0, 0);\
  acc[0][2] = __builtin_amdgcn_mfma_f32_16x16x32_bf16(sa0, sb2, acc[0][2], 0, 0, 0);\
  acc[0][3] = __builtin_amdgcn_mfma_f32_16x16x32_bf16(sa0, sb3, acc[0][3], 0, 0, 0);\
  acc[1][0] = __builtin_amdgcn_mfma_f32_16x16x32_bf16(sa1, sb0, acc[1][0], 0, 0, 0);\
  acc[1][1] = __builtin_amdgcn_mfma_f32_16x16x32_bf16(sa1, sb1, acc[1][1], 0, 0, 0);\
  acc[1][2] = __builtin_amdgcn_mfma_f32_16x16x32_bf16(sa1, sb2, acc[1][2], 0, 0, 0);\
  acc[1][3] = __builtin_amdgcn_mfma_f32_16x16x32_bf16(sa1, sb3, acc[1][3], 0, 0, 0);

__global__ __launch_bounds__(256, 6)
void k4s_gemm(const unsigned short* __restrict__ HTI, const unsigned short* __restrict__ EBI,
              unsigned short* __restrict__ R) {
  int tid = threadIdx.x, w = tid >> 6, lane = tid & 63;
  // 1536 blocks; XCD j (= bid&7) owns db-slice j, all {qb, b, h}
  int db = blockIdx.x & 7;
  int sub = blockIdx.x >> 3;                     // 0..191
  int qb = sub % 24;
  int rest = sub / 24;                           // 0..7
  int b = rest & 3, hh = rest >> 2;
  int Q0w = qb * 128 + w * 32;                   // waves q-stacked
  int D0w = db * 64;

  int v_lo = (Q0w > 951) ? ((Q0w - 951) & ~31) : 0;
  int v_hi = Q0w + 2080; if (v_hi > 4128) v_hi = 4128;
  int ntt = (v_hi - v_lo) >> 5;                  // 65..95 total steps
  int nh0 = (ntt + 1) >> 1;
  int v_st = v_lo + (hh ? nh0 * 32 : 0);         // this half's window start
  int nt = hh ? (ntt - nh0) : nh0;               // 32..48 steps

  const char* hb = (const char*)HTI + (size_t)b * HTI_BATCH_BYTES;
  const char* eb = (const char*)EBI;

  int S0 = 3056 - Q0w + v_st;                    // frag selector (mult of 16, in [0,5104])
  int S1 = S0 - 16;
  int cA0 = (((S0 >> 4) & 1) * 256 + (S0 >> 5)) * 1024;
  int cA1 = (((S1 >> 4) & 1) * 256 + (S1 >> 5)) * 1024;
  int kb0 = v_st >> 5, dt0 = D0w >> 4;
  int cB0 = ((dt0 + 0) * EBI_KB + kb0) * 1024;
  int cB1 = ((dt0 + 1) * EBI_KB + kb0) * 1024;
  int cB2 = ((dt0 + 2) * EBI_KB + kb0) * 1024;
  int cB3 = ((dt0 + 3) * EBI_KB + kb0) * 1024;
  int vo = lane * 16;

  f32x4 acc[2][4];
#pragma unroll
  for (int a1 = 0; a1 < 2; ++a1)
#pragma unroll
    for (int a2 = 0; a2 < 4; ++a2) { f32x4 z = {0.f, 0.f, 0.f, 0.f}; acc[a1][a2] = z; }

  bf16x8 a00, a01, b00, b01, b02, b03;
  bf16x8 a10, a11, b10, b11, b12, b13;
  bf16x8 a20, a21, b20, b21, b22, b23;

  LOADSET(a00, a01, b00, b01, b02, b03, 0);
  LOADSET(a10, a11, b10, b11, b12, b13, 1);

  int t = 0;
  for (;;) {
    LOADSET(a20, a21, b20, b21, b22, b23, t + 2);
    MMSET(a00, a01, b00, b01, b02, b03);
    if (++t == nt) break;
    LOADSET(a00, a01, b00, b01, b02, b03, t + 2);
    MMSET(a10, a11, b10, b11, b12, b13);
    if (++t == nt) break;
    LOADSET(a10, a11, b10, b11, b12, b13, t + 2);
    MMSET(a20, a21, b20, b21, b22, b23);
    if (++t == nt) break;
  }

  // Store partial sums to R[hh][b][q][d] (bf16)
  unsigned short* Rh = R + (size_t)hh * RHALF + ((size_t)b * RQ) * ND;
  int col = lane & 15, rb4 = (lane >> 4) * 4;
#pragma unroll
  for (int nf = 0; nf < 4; ++nf) {
    int dcol = D0w + nf * 16 + col;
#pragma unroll
    for (int mf = 0; mf < 2; ++mf) {
#pragma unroll
      for (int j = 0; j < 4; ++j) {
        int q = Q0w + mf * 16 + rb4 + j;
        Rh[(size_t)q * ND + dcol] = f2bf(acc[mf][nf][j]);
      }
    }
  }
}

// ---------- k5: streaming epilogue: out = x + (R0+R1 + boundary)/S ----------
__global__ __launch_bounds__(256)
void k5_out(const int* __restrict__ pos, const int* __restrict__ rs,
            const float* __restrict__ x, const float* __restrict__ emb,
            const unsigned short* __restrict__ R, float* __restrict__ out) {
  int row = blockIdx.x;                          // 8192 = B*S rows
  int b = row >> 11, i = row & 2047;
  int q = pos[b * NS + i];                       // uniform per block
  const int* rsb = rs + b * RSW;
  int cge = (q >= NM) ? rsb[q - NM + 1] : 0;     // #{pos_j <= q-M}
  int cle = (q + NM < NP) ? (NS - rsb[q + NM]) : 0;  // #{pos_j >= q+M}
  float fg = (float)cge, fl = (float)cle;
  int d0 = threadIdx.x * 2;
  const unsigned short* r0 = R + ((size_t)b * RQ + q) * ND + d0;
  const unsigned short* r1 = r0 + RHALF;
  unsigned int u0 = *(const unsigned int*)r0;    // 2 x bf16
  unsigned int u1 = *(const unsigned int*)r1;
  float ra = bfbits2f(u0 & 0xffffu) + bfbits2f(u1 & 0xffffu);
  float rb = bfbits2f(u0 >> 16) + bfbits2f(u1 >> 16);
  float e0a = emb[d0], e0b = emb[d0 + 1];
  float eMa = emb[(size_t)(NV - 1) * ND + d0], eMb = emb[(size_t)(NV - 1) * ND + d0 + 1];
  const float* xp = x + (size_t)row * ND + d0;
  float2 xx = *(const float2*)xp;
  float2 o;
  o.x = xx.x + (ra + fg * eMa + fl * e0a) * (1.0f / (float)NS);
  o.y = xx.y + (rb + fg * eMb + fl * e0b) * (1.0f / (float)NS);
  *(float2*)(out + (size_t)row * ND + d0) = o;
}

extern "C" void kernel_launch(void* const* d_in, const int* in_sizes, int n_in,
                              void* d_out, int out_size, void* d_ws, size_t ws_size,
                              hipStream_t stream) {
  const float* x = (const float*)d_in[0];
  const float* emb = (const float*)d_in[1];
  const int* pos = (const int*)d_in[2];
  float* out = (float*)d_out;

  char* ws = (char*)d_ws;
  unsigned short* R = (unsigned short*)(ws);                  // 2 halves x 12.6MB = 25,165,824 B
  unsigned short* HTI = (unsigned short*)(ws + 25165824);     // 2,097,152 B
  unsigned short* EBI = (unsigned short*)(ws + 27262976);     // 4,227,072 B
  int* rs = (int*)(ws + 31490048);                            // 49,280 B
  // total ws use ~31.5 MB

  hipLaunchKernelGGL(k_prep, dim3(1084), dim3(256), 0, stream, pos, emb, HTI, EBI, rs);
  hipLaunchKernelGGL(k4s_gemm, dim3(1536), dim3(256), 0, stream, HTI, EBI, R);
  hipLaunchKernelGGL(k5_out, dim3(8192), dim3(256), 0, stream, pos, rs, x, emb, R, out);
}